// Round 11
// baseline (3542.517 us; speedup 1.0000x reference)
//
#include <hip/hip_runtime.h>

#define TPB 256

// Block-per-board, ONE __syncthreads per step, zero per-step global traffic.
// - xp (probs) and xs (board) live in LDS, flushed once at kernel end.
// - scores double-buffered (R10-validated race-free scheme): ARG reads scur
//   (read-only all step); C writes snext for {affected, !=fcell, scur>=0};
//   copier (t<81) writes the complement + snext[fcell] = -1. Writer sets
//   disjoint; all cross-wave read/write pairs barrier-separated.
// - every wave: redundant shfl-butterfly argmax, private u8 cnt copy, W1 in
//   registers (w1r), redundant recompute of the 3 dirty H1 rows (identical
//   bits; own reads ordered by the per-wave in-order DS pipe + wave_barrier).
// - F+C fused per-v: lane (slot,v) computes y directly (h redundancy is
//   horizontal across lanes -> free); shuffle softmax in ascending v order.
// Decision math (H1, hidden, y, softmax) is f64 with one fixed canonical
// summation structure (4 j-stripes, fixed combine; ascending shuffles):
// equal count-triples give bit-identical scores -> np first-index tie-breaks
// via strict-> comparisons in index order. (Scheme validated R2-R10.)
//
// Affected set of one fill = 9 row + 9 col + 4 off-row/off-col box = 22 slots.

__device__ __forceinline__ int affected_cell(int slot, int fr, int fc) {
    if (slot < 9)  return fr * 9 + slot;            // row cells
    if (slot < 18) return (slot - 9) * 9 + fc;      // col cells
    int r0 = (fr / 3) * 3, c0 = (fc / 3) * 3;       // box cells off-row/off-col
    int dr = fr - r0, dc = fc - c0;
    int rA = r0 + (dr == 0 ? 1 : 0), rB = r0 + (dr == 2 ? 1 : 2);
    int cA = c0 + (dc == 0 ? 1 : 0), cB = c0 + (dc == 2 ? 1 : 2);
    int k = slot - 18;
    return ((k < 2) ? rA : rB) * 9 + ((k & 1) ? cB : cA);
}

// Fused F+C: 54 lanes = 6 slots x 9 v. init mode: c0>=0 -> cell = c0+slot;
// main mode: c0<0 -> cell = affected_cell(slot, fr, fcol).
__device__ __forceinline__ void fc_pass(int c0, int fcell, int fr, int fcol,
    int l, int slotBase,
    const double* __restrict__ H1, const double* __restrict__ W2Td,
    const double* __restrict__ scur, double* __restrict__ snext,
    int* __restrict__ pos_l, float* __restrict__ xp)
{
    if (l < 54) {
        int ls = l / 9, v = l - 9 * ls;
        int slot = slotBase + ls;
        if (slot < 22) {
            int cell = (c0 >= 0) ? (c0 + slot) : affected_cell(slot, fr, fcol);
            if (cell < 81 && cell != fcell && scur[cell] >= 0.0) {
                int rr = cell / 9, cc = cell - 9 * rr;
                int bx = (rr / 3) * 3 + cc / 3;
                const double* Hr = H1 + rr * 101;
                const double* Hc = H1 + (9 + cc) * 101;
                const double* Hb = H1 + (18 + bx) * 101;
                const double* Wv = W2Td + v;
                double a0 = 0.0, a1 = 0.0, a2 = 0.0, a3 = 0.0;
#pragma unroll 5
                for (int j = 0; j < 25; j++) {
                    double h0 = Hr[j]      + Hc[j]      + Hb[j];
                    double h1 = Hr[j + 25] + Hc[j + 25] + Hb[j + 25];
                    double h2 = Hr[j + 50] + Hc[j + 50] + Hb[j + 50];
                    double h3 = Hr[j + 75] + Hc[j + 75] + Hb[j + 75];
                    h0 = h0 > 0.0 ? h0 : 0.0;
                    h1 = h1 > 0.0 ? h1 : 0.0;
                    h2 = h2 > 0.0 ? h2 : 0.0;
                    h3 = h3 > 0.0 ? h3 : 0.0;
                    a0 = fma(h0, Wv[ j       * 9], a0);
                    a1 = fma(h1, Wv[(j + 25) * 9], a1);
                    a2 = fma(h2, Wv[(j + 50) * 9], a2);
                    a3 = fma(h3, Wv[(j + 75) * 9], a3);
                }
                double y = (a0 + a1) + (a2 + a3);
                const int base = ls * 9;               // wave-lane base of slot
                double m = __shfl(y, base);
#pragma unroll
                for (int k = 1; k < 9; k++) m = fmax(m, __shfl(y, base + k));
                double e = exp(y - m);
                double sum = 0.0;
#pragma unroll
                for (int k = 0; k < 9; k++) sum += __shfl(e, base + k);
                double inv = 1.0 / sum;
                double pr = e * inv;
                xp[cell * 9 + v] = (float)pr;
                double best = -1.0; int bp = 0;
#pragma unroll
                for (int k = 0; k < 9; k++) {
                    double pk = __shfl(pr, base + k);
                    if (pk > best) { best = pk; bp = k; }  // strict > : first-index
                }
                if (v == 0) { snext[cell] = best; pos_l[cell] = bp; }
            }
        }
    }
    __builtin_amdgcn_wave_barrier();
}

__global__ __launch_bounds__(TPB, 4) void sudoku_kernel(
    const float* __restrict__ x_in,
    const float* __restrict__ W1,
    const float* __restrict__ W2,
    float* __restrict__ out,
    int nb)
{
    const int b = blockIdx.x;
    const int t = threadIdx.x;
    const int W = t >> 6, l = t & 63;
    const int slotBase = W * 6;

    // 37,444 B -> 4 blocks/CU (16 waves/CU)
    __shared__ double H1[27 * 101];          // 21,816 B (odd stride)
    __shared__ double W2Td[100 * 9];         //  7,200 B
    __shared__ float  xp[729];               //  2,916 B probs (LDS-resident)
    __shared__ float  xs[729];               //  2,916 B board (LDS-resident)
    __shared__ double sb0[81], sb1[81];      //  1,296 B score double-buffer
    __shared__ int    pos_l[81];             //    324 B
    __shared__ unsigned char cntw[4 * 244];  //    976 B per-wave cnt copies

    const float* xb = x_in + (size_t)b * 729;

    // init: xs/xp from input + W2Td (block-split)
    for (int i = t; i < 729; i += TPB) { float v = xb[i]; xp[i] = v; xs[i] = v; }
    for (int i = t; i < 900; i += TPB) {
        int v = i / 100, j = i - 100 * v;
        W2Td[j * 9 + v] = (double)W2[i];
    }
    // empty flags (0.0 sentinel) + pos init
    if (t < 81) {
        float s = 0.f;
#pragma unroll
        for (int v = 0; v < 9; v++) s += xb[t * 9 + v];
        sb0[t] = (s == 0.f) ? 0.0 : -1.0;
        pos_l[t] = 0;
    }
    // per-wave cnt copy (exact small ints)
    unsigned char* cw = cntw + W * 244;
#pragma unroll
    for (int r = 0; r < 4; r++) {
        int o = r * 64 + l;
        if (o < 243) {
            int g = o / 9, v = o - 9 * g;
            float s = 0.f;
            if (g < 9) {
                int base = g * 9;
#pragma unroll
                for (int k = 0; k < 9; k++) s += xb[(base + k) * 9 + v];
            } else if (g < 18) {
                int c = g - 9;
#pragma unroll
                for (int k = 0; k < 9; k++) s += xb[(c + 9 * k) * 9 + v];
            } else {
                int bx = g - 18;
                int base = (bx / 3) * 27 + (bx % 3) * 3;
#pragma unroll
                for (int k = 0; k < 9; k++) s += xb[(base + (k / 3) * 9 + (k % 3)) * 9 + v];
            }
            cw[o] = (unsigned char)(int)s;
        }
    }
    // per-lane W1 slice for the main-loop H phase (fixed (gi,j) per k)
    float w1r[5][9];
#pragma unroll
    for (int k = 0; k < 5; k++) {
        int o = k * 64 + l; if (o >= 300) o = 0;
        int gi = o / 100, j = o - 100 * gi;
#pragma unroll
        for (int v = 0; v < 9; v++) w1r[k][v] = W1[j * 27 + gi * 9 + v];
    }
    __builtin_amdgcn_wave_barrier();
    // full H1 init, redundant per wave (identical bits; own reads see own writes)
    for (int r = 0; r < 43; r++) {
        int o = r * 64 + l;
        if (o < 2700) {
            int g = o / 100, j = o - 100 * g;
            int type = (g >= 18) ? 2 : (g >= 9 ? 1 : 0);
            const float* w = W1 + j * 27 + type * 9;
            const unsigned char* cg = cw + g * 9;
            double s = 0.0;
#pragma unroll
            for (int v = 0; v < 9; v++) s = fma((double)w[v], (double)cg[v], s);
            H1[g * 101 + j] = s;
        }
    }
    __syncthreads();   // flags + W2Td + H1 visible to all waves

    // initial probs/scores for all empty cells (own slots, 4 passes; snext=sb0:
    // per-wave-disjoint cells -> no conflicting writers)
    for (int p = 0; p < 4; p++)
        fc_pass(p * 22, -1, 0, 0, l, slotBase, H1, W2Td, sb0, sb0, pos_l, xp);
    __syncthreads();   // all scores visible

    int ne = __popcll(__ballot(sb0[l] >= 0.0));
    ne += __popcll(__ballot((l < 17) && (sb0[64 + l] >= 0.0)));

    double* scur = sb0;
    double* snext = sb1;

    // main loop: ONE block barrier per step, no global memory touched
    for (int step = 0; step < ne; ++step) {
        // ARG: redundant per-wave butterfly argmax over scur (read-only all step)
        double s = scur[l]; int idx = l;
        if (l < 17) {
            double s2 = scur[64 + l];
            if (s2 > s) { s = s2; idx = 64 + l; }   // tie keeps lower idx
        }
#pragma unroll
        for (int off = 1; off < 64; off <<= 1) {
            double s2 = __shfl_xor(s, off);
            int    i2 = __shfl_xor(idx, off);
            if (s2 > s || (s2 == s && i2 < idx)) { s = s2; idx = i2; }
        }
        const int fcell = idx;
        const int bv = pos_l[fcell];
        const int frow = fcell / 9, fcol = fcell - 9 * frow;
        const int fbx = (frow / 3) * 3 + fcol / 3;

        if (t == 0) xs[fcell * 9 + bv] = 1.0f;     // record fill (LDS)
        if (l == 0) {                              // each wave: own cnt copy
            cw[frow * 9 + bv] += 1;
            cw[(9 + fcol) * 9 + bv] += 1;
            cw[(18 + fbx) * 9 + bv] += 1;
        }
        __builtin_amdgcn_wave_barrier();

        // H: 3 dirty rows, redundant per wave (register W1, canonical v-order)
#pragma unroll
        for (int k = 0; k < 5; k++) {
            int o = k * 64 + l;
            if (o < 300) {
                int gi = o / 100, j = o - 100 * gi;
                int g = (gi == 0) ? frow : (gi == 1) ? (9 + fcol) : (18 + fbx);
                const unsigned char* cg = cw + g * 9;
                double h = 0.0;
#pragma unroll
                for (int v = 0; v < 9; v++)
                    h = fma((double)w1r[k][v], (double)cg[v], h);
                H1[g * 101 + j] = h;
            }
        }
        __builtin_amdgcn_wave_barrier();

        // F+C fused for the 22 affected cells (writes snext/pos_l/xp)
        fc_pass(-1, fcell, frow, fcol, l, slotBase, H1, W2Td, scur, snext, pos_l, xp);

        // copier: carry the complement scur -> snext; fcell gets -1
        if (t < 81) {
            int cr = t / 9, cc = t - 9 * cr;
            bool aff = (cr == frow) || (cc == fcol) ||
                       ((cr / 3) == (frow / 3) && (cc / 3) == (fcol / 3));
            double sc = scur[t];
            if (t == fcell) snext[t] = -1.0;
            else if (!(aff && sc >= 0.0)) snext[t] = sc;
        }
        __syncthreads();
        double* tmp = scur; scur = snext; snext = tmp;
    }

    // single coalesced flush
    float* outp = out + (size_t)b * 729;
    float* outx = out + (size_t)nb * 729 + (size_t)b * 729;
    for (int i = t; i < 729; i += TPB) { outp[i] = xp[i]; outx[i] = xs[i]; }
}

extern "C" void kernel_launch(void* const* d_in, const int* in_sizes, int n_in,
                              void* d_out, int out_size, void* d_ws, size_t ws_size,
                              hipStream_t stream) {
    const float* x  = (const float*)d_in[0];
    const float* W1 = (const float*)d_in[1];
    const float* W2 = (const float*)d_in[2];
    int nb = in_sizes[0] / 729;
    (void)n_in; (void)out_size; (void)d_ws; (void)ws_size;
    sudoku_kernel<<<nb, TPB, 0, stream>>>(x, W1, W2, (float*)d_out, nb);
}

// Round 12
// 3321.749 us; speedup vs baseline: 1.0665x; 1.0665x over previous
//
#include <hip/hip_runtime.h>

#define TPB 256

// Block-per-board, ONE __syncthreads per step, zero per-step global traffic
// except L1-hot W1 reads (10.8 KB, shared by all blocks).
// - xp (probs) and xs (board) live in LDS, flushed once at kernel end.
// - scores double-buffered (R10-validated race-free scheme): ARG reads scur
//   (read-only all step); C writes snext for {affected, !=fcell, scur>=0};
//   copier (t<81) writes the complement + snext[fcell] = -1. Writer sets
//   disjoint; all cross-wave read/write pairs barrier-separated.
// - every wave: redundant shfl-butterfly argmax, private u8 cnt copy,
//   redundant recompute of the 3 dirty H1 rows (identical bits; own reads
//   ordered by the per-wave in-order DS pipe + wave_barrier fences).
// - F+C fused per-v: lane (slot,v) computes y directly (h redundancy is
//   horizontal across lanes -> free); shuffle softmax in ascending v order.
// - NO register W1 cache: R11 showed it spills at the 64-VGPR occupancy
//   target and scratch traffic dwarfs the saved L1 reads.
// Decision math (H1, hidden, y, softmax) is f64 with one fixed canonical
// summation structure (4 j-stripes, fixed combine; ascending shuffles):
// equal count-triples give bit-identical scores -> np first-index tie-breaks
// via strict-> comparisons in index order. (Scheme validated R2-R11.)
//
// Affected set of one fill = 9 row + 9 col + 4 off-row/off-col box = 22 slots.

__device__ __forceinline__ int affected_cell(int slot, int fr, int fc) {
    if (slot < 9)  return fr * 9 + slot;            // row cells
    if (slot < 18) return (slot - 9) * 9 + fc;      // col cells
    int r0 = (fr / 3) * 3, c0 = (fc / 3) * 3;       // box cells off-row/off-col
    int dr = fr - r0, dc = fc - c0;
    int rA = r0 + (dr == 0 ? 1 : 0), rB = r0 + (dr == 2 ? 1 : 2);
    int cA = c0 + (dc == 0 ? 1 : 0), cB = c0 + (dc == 2 ? 1 : 2);
    int k = slot - 18;
    return ((k < 2) ? rA : rB) * 9 + ((k & 1) ? cB : cA);
}

// Fused F+C: 54 lanes = 6 slots x 9 v. init mode: c0>=0 -> cell = c0+slot;
// main mode: c0<0 -> cell = affected_cell(slot, fr, fcol).
__device__ __forceinline__ void fc_pass(int c0, int fcell, int fr, int fcol,
    int l, int slotBase,
    const double* __restrict__ H1, const double* __restrict__ W2Td,
    const double* __restrict__ scur, double* __restrict__ snext,
    int* __restrict__ pos_l, float* __restrict__ xp)
{
    if (l < 54) {
        int ls = l / 9, v = l - 9 * ls;
        int slot = slotBase + ls;
        if (slot < 22) {
            int cell = (c0 >= 0) ? (c0 + slot) : affected_cell(slot, fr, fcol);
            if (cell < 81 && cell != fcell && scur[cell] >= 0.0) {
                int rr = cell / 9, cc = cell - 9 * rr;
                int bx = (rr / 3) * 3 + cc / 3;
                const double* Hr = H1 + rr * 101;
                const double* Hc = H1 + (9 + cc) * 101;
                const double* Hb = H1 + (18 + bx) * 101;
                const double* Wv = W2Td + v;
                double a0 = 0.0, a1 = 0.0, a2 = 0.0, a3 = 0.0;
#pragma unroll 5
                for (int j = 0; j < 25; j++) {
                    double h0 = Hr[j]      + Hc[j]      + Hb[j];
                    double h1 = Hr[j + 25] + Hc[j + 25] + Hb[j + 25];
                    double h2 = Hr[j + 50] + Hc[j + 50] + Hb[j + 50];
                    double h3 = Hr[j + 75] + Hc[j + 75] + Hb[j + 75];
                    h0 = h0 > 0.0 ? h0 : 0.0;
                    h1 = h1 > 0.0 ? h1 : 0.0;
                    h2 = h2 > 0.0 ? h2 : 0.0;
                    h3 = h3 > 0.0 ? h3 : 0.0;
                    a0 = fma(h0, Wv[ j       * 9], a0);
                    a1 = fma(h1, Wv[(j + 25) * 9], a1);
                    a2 = fma(h2, Wv[(j + 50) * 9], a2);
                    a3 = fma(h3, Wv[(j + 75) * 9], a3);
                }
                double y = (a0 + a1) + (a2 + a3);
                const int base = ls * 9;               // wave-lane base of slot
                double m = __shfl(y, base);
#pragma unroll
                for (int k = 1; k < 9; k++) m = fmax(m, __shfl(y, base + k));
                double e = exp(y - m);
                double sum = 0.0;
#pragma unroll
                for (int k = 0; k < 9; k++) sum += __shfl(e, base + k);
                double inv = 1.0 / sum;
                double pr = e * inv;
                xp[cell * 9 + v] = (float)pr;
                double best = -1.0; int bp = 0;
#pragma unroll
                for (int k = 0; k < 9; k++) {
                    double pk = __shfl(pr, base + k);
                    if (pk > best) { best = pk; bp = k; }  // strict > : first-index
                }
                if (v == 0) { snext[cell] = best; pos_l[cell] = bp; }
            }
        }
    }
    __builtin_amdgcn_wave_barrier();
}

__global__ __launch_bounds__(TPB, 4) void sudoku_kernel(
    const float* __restrict__ x_in,
    const float* __restrict__ W1,
    const float* __restrict__ W2,
    float* __restrict__ out,
    int nb)
{
    const int b = blockIdx.x;
    const int t = threadIdx.x;
    const int W = t >> 6, l = t & 63;
    const int slotBase = W * 6;

    // 37,444 B -> 4 blocks/CU (16 waves/CU)
    __shared__ double H1[27 * 101];          // 21,816 B (odd stride)
    __shared__ double W2Td[100 * 9];         //  7,200 B
    __shared__ float  xp[729];               //  2,916 B probs (LDS-resident)
    __shared__ float  xs[729];               //  2,916 B board (LDS-resident)
    __shared__ double sb0[81], sb1[81];      //  1,296 B score double-buffer
    __shared__ int    pos_l[81];             //    324 B
    __shared__ unsigned char cntw[4 * 244];  //    976 B per-wave cnt copies

    const float* xb = x_in + (size_t)b * 729;

    // init: xs/xp from input + W2Td (block-split)
    for (int i = t; i < 729; i += TPB) { float v = xb[i]; xp[i] = v; xs[i] = v; }
    for (int i = t; i < 900; i += TPB) {
        int v = i / 100, j = i - 100 * v;
        W2Td[j * 9 + v] = (double)W2[i];
    }
    // empty flags (0.0 sentinel) + pos init
    if (t < 81) {
        float s = 0.f;
#pragma unroll
        for (int v = 0; v < 9; v++) s += xb[t * 9 + v];
        sb0[t] = (s == 0.f) ? 0.0 : -1.0;
        pos_l[t] = 0;
    }
    // per-wave cnt copy (exact small ints)
    unsigned char* cw = cntw + W * 244;
#pragma unroll
    for (int r = 0; r < 4; r++) {
        int o = r * 64 + l;
        if (o < 243) {
            int g = o / 9, v = o - 9 * g;
            float s = 0.f;
            if (g < 9) {
                int base = g * 9;
#pragma unroll
                for (int k = 0; k < 9; k++) s += xb[(base + k) * 9 + v];
            } else if (g < 18) {
                int c = g - 9;
#pragma unroll
                for (int k = 0; k < 9; k++) s += xb[(c + 9 * k) * 9 + v];
            } else {
                int bx = g - 18;
                int base = (bx / 3) * 27 + (bx % 3) * 3;
#pragma unroll
                for (int k = 0; k < 9; k++) s += xb[(base + (k / 3) * 9 + (k % 3)) * 9 + v];
            }
            cw[o] = (unsigned char)(int)s;
        }
    }
    __builtin_amdgcn_wave_barrier();
    // full H1 init, redundant per wave (identical bits; own reads see own writes)
    for (int r = 0; r < 43; r++) {
        int o = r * 64 + l;
        if (o < 2700) {
            int g = o / 100, j = o - 100 * g;
            int type = (g >= 18) ? 2 : (g >= 9 ? 1 : 0);
            const float* w = W1 + j * 27 + type * 9;
            const unsigned char* cg = cw + g * 9;
            double s = 0.0;
#pragma unroll
            for (int v = 0; v < 9; v++) s = fma((double)w[v], (double)cg[v], s);
            H1[g * 101 + j] = s;
        }
    }
    __syncthreads();   // flags + W2Td + H1 visible to all waves

    // initial probs/scores for all empty cells (own slots, 4 passes; snext=sb0:
    // per-wave-disjoint cells -> no conflicting writers)
    for (int p = 0; p < 4; p++)
        fc_pass(p * 22, -1, 0, 0, l, slotBase, H1, W2Td, sb0, sb0, pos_l, xp);
    __syncthreads();   // all scores visible

    int ne = __popcll(__ballot(sb0[l] >= 0.0));
    ne += __popcll(__ballot((l < 17) && (sb0[64 + l] >= 0.0)));

    double* scur = sb0;
    double* snext = sb1;

    // main loop: ONE block barrier per step; only L1-hot W1 global reads
    for (int step = 0; step < ne; ++step) {
        // ARG: redundant per-wave butterfly argmax over scur (read-only all step)
        double s = scur[l]; int idx = l;
        if (l < 17) {
            double s2 = scur[64 + l];
            if (s2 > s) { s = s2; idx = 64 + l; }   // tie keeps lower idx
        }
#pragma unroll
        for (int off = 1; off < 64; off <<= 1) {
            double s2 = __shfl_xor(s, off);
            int    i2 = __shfl_xor(idx, off);
            if (s2 > s || (s2 == s && i2 < idx)) { s = s2; idx = i2; }
        }
        const int fcell = idx;
        const int bv = pos_l[fcell];
        const int frow = fcell / 9, fcol = fcell - 9 * frow;
        const int fbx = (frow / 3) * 3 + fcol / 3;

        if (t == 0) xs[fcell * 9 + bv] = 1.0f;     // record fill (LDS)
        if (l == 0) {                              // each wave: own cnt copy
            cw[frow * 9 + bv] += 1;
            cw[(9 + fcol) * 9 + bv] += 1;
            cw[(18 + fbx) * 9 + bv] += 1;
        }
        __builtin_amdgcn_wave_barrier();

        // H: 3 dirty rows, redundant per wave (W1 from global/L1, canonical order)
#pragma unroll
        for (int k = 0; k < 5; k++) {
            int o = k * 64 + l;
            if (o < 300) {
                int gi = o / 100, j = o - 100 * gi;
                int g = (gi == 0) ? frow : (gi == 1) ? (9 + fcol) : (18 + fbx);
                const float* w = W1 + j * 27 + gi * 9;
                const unsigned char* cg = cw + g * 9;
                double h = 0.0;
#pragma unroll
                for (int v = 0; v < 9; v++)
                    h = fma((double)w[v], (double)cg[v], h);
                H1[g * 101 + j] = h;
            }
        }
        __builtin_amdgcn_wave_barrier();

        // F+C fused for the 22 affected cells (writes snext/pos_l/xp)
        fc_pass(-1, fcell, frow, fcol, l, slotBase, H1, W2Td, scur, snext, pos_l, xp);

        // copier: carry the complement scur -> snext; fcell gets -1
        if (t < 81) {
            int cr = t / 9, cc = t - 9 * cr;
            bool aff = (cr == frow) || (cc == fcol) ||
                       ((cr / 3) == (frow / 3) && (cc / 3) == (fcol / 3));
            double sc = scur[t];
            if (t == fcell) snext[t] = -1.0;
            else if (!(aff && sc >= 0.0)) snext[t] = sc;
        }
        __syncthreads();
        double* tmp = scur; scur = snext; snext = tmp;
    }

    // single coalesced flush
    float* outp = out + (size_t)b * 729;
    float* outx = out + (size_t)nb * 729 + (size_t)b * 729;
    for (int i = t; i < 729; i += TPB) { outp[i] = xp[i]; outx[i] = xs[i]; }
}

extern "C" void kernel_launch(void* const* d_in, const int* in_sizes, int n_in,
                              void* d_out, int out_size, void* d_ws, size_t ws_size,
                              hipStream_t stream) {
    const float* x  = (const float*)d_in[0];
    const float* W1 = (const float*)d_in[1];
    const float* W2 = (const float*)d_in[2];
    int nb = in_sizes[0] / 729;
    (void)n_in; (void)out_size; (void)d_ws; (void)ws_size;
    sudoku_kernel<<<nb, TPB, 0, stream>>>(x, W1, W2, (float*)d_out, nb);
}